// Round 8
// baseline (180.939 us; speedup 1.0000x reference)
//
#include <hip/hip_runtime.h>
#include <cstddef>
#include <cstdint>

// GMM E-step: N=200000, K=16, D=64, fp32 in/out.
// R13: R9 structure (verified best: estep 71.5us) + __launch_bounds__(256,4)
// on estep, setprio removed (R12: null/-1us). Diagnosis: estep is LATENCY-
// bound with starved TLP, not issue-bound. Occupancy law from R9/R10/R11
// counters: occ% ~= 2000/VGPR_Count (smooth 1/regs, not binned) -> the
// true per-wave allocation is ~140-160 regs: the compiler parks af[4][4]
// (64 regs) + tk4 in AGPRs (gfx950 unified file; MFMA reads A from AGPR),
// invisible in VGPR_Count but charged against occupancy. launch_bounds
// (256,4) caps total VGPR+AGPR at 128/wave, forcing af re-loads from L2
// (cheap, resident) and doubling resident waves -> latency hiding.
// Precompute = R9 verified (single-wave register Cholesky + LDS handoff +
// register fwd-subst inverse, negated tv, 16x16 WA swizzle).

#define GMM_D 64
#define GMM_K 16

typedef _Float16 half8 __attribute__((ext_vector_type(8)));
typedef float f32x4 __attribute__((ext_vector_type(4)));

// ws: WA [16 comps][16 frags][64 lanes][8 f16] = 262144 B, then tv, cc (f32)
#define WA_BYTES (GMM_K * 16 * 64 * 8 * 2)

__device__ __forceinline__ float fast_rsqrt(float x) {
#if __has_builtin(__builtin_amdgcn_rsqf)
    // v_rsq_f32 (~1 ulp) + one Newton step -> full fp32 accuracy
    const float r = __builtin_amdgcn_rsqf(x);
    return r * (1.5f - 0.5f * x * r * r);
#else
    return 1.0f / sqrtf(x);
#endif
}

// broadcast lane l's value of v to all lanes (l compile-time after unroll)
__device__ __forceinline__ float lane_bcast(float v, int l) {
    return __int_as_float(__builtin_amdgcn_readlane(__float_as_int(v), l));
}

// ---------------------------------------------------------------------------
// Precompute (R9-verified): one WAVE per component. Phase 1: register
// Cholesky via readlane broadcasts. Phase 2: register forward-substitution
// inverse fed by wave-uniform ds_read_b128 of L rows. At most one 64-float
// register array live at a time (R7 lesson: two live arrays -> spills).
// tv stored NEGATED so estep's MFMA C-init needs no negate (R9).
// ---------------------------------------------------------------------------
__global__ __launch_bounds__(64) void gmm_precompute_kernel(
    const float* __restrict__ pi, const float* __restrict__ mus,
    const float* __restrict__ covs, _Float16* __restrict__ WA,
    float* __restrict__ tv, float* __restrict__ cc)
{
    const int k = blockIdx.x;
    const int r = threadIdx.x;  // lane id

    __shared__ alignas(16) float Ls[GMM_D][68];  // L rows, upper tri zeroed;
                                                 // 272 B stride: 16B-aligned
    __shared__ float Wv[GMM_D][GMM_D + 1];       // W = L^{-1}, for epilogue

    // ---- load row r of Sigma into registers (16x float4, L2-resident) ----
    float A_r[GMM_D];
    {
        const float4* src = reinterpret_cast<const float4*>(
            covs + (size_t)k * GMM_D * GMM_D + (size_t)r * GMM_D);
        #pragma unroll
        for (int u = 0; u < GMM_D / 4; ++u) {
            const float4 v = src[u];
            A_r[4 * u + 0] = v.x; A_r[4 * u + 1] = v.y;
            A_r[4 * u + 2] = v.z; A_r[4 * u + 3] = v.w;
        }
    }

    // ---- Phase 1: register Cholesky, right-looking, zero barriers ----
    float mydiag = 1.0f, myrs = 1.0f;
    #pragma unroll
    for (int j = 0; j < GMM_D; ++j) {
        const float pivot = lane_bcast(A_r[j], j);   // lane j: valid diag
        const float rs = fast_rsqrt(pivot);
        const float valj = A_r[j] * rs;              // L[r][j]; lane j: sqrt(pivot)
        if (r == j) { mydiag = valj; myrs = rs; }
        A_r[j] = valj;
        #pragma unroll
        for (int p = j + 1; p < GMM_D; ++p)          // rank-1 trailing update
            A_r[p] -= valj * lane_bcast(valj, p);    // L[p][j] from lane p
    }

    // ---- handoff: dump L rows to LDS, upper triangle zeroed. A_r dies. ----
    #pragma unroll
    for (int p = 0; p < GMM_D; ++p)
        Ls[r][p] = (p <= r) ? A_r[p] : 0.0f;
    __syncthreads();   // single wave: cheap

    // ---- Phase 2: lane r solves L w = e_r; only w[64] live in registers ----
    float w[GMM_D];
    #pragma unroll
    for (int i = 0; i < GMM_D; ++i) w[i] = 0.0f;

    #pragma unroll
    for (int i = 0; i < GMM_D; ++i) {
        const f32x4* Lrow = reinterpret_cast<const f32x4*>(&Ls[i][0]);
        float a0 = 0.0f, a1 = 0.0f, a2 = 0.0f, a3 = 0.0f;
        #pragma unroll
        for (int u = 0; u <= (i >> 2); ++u) {        // zeros make tail exact
            const f32x4 lv = Lrow[u];
            a0 -= lv[0] * w[4 * u + 0];
            a1 -= lv[1] * w[4 * u + 1];
            a2 -= lv[2] * w[4 * u + 2];
            a3 -= lv[3] * w[4 * u + 3];
        }
        const float invd = lane_bcast(myrs, i);      // 1/L[i][i]
        const float dlt = (r == i) ? 1.0f : 0.0f;
        w[i] = (dlt + (a0 + a1) + (a2 + a3)) * invd;
    }

    // ---- dump W to LDS (lane r holds column r -> write transposed) ----
    #pragma unroll
    for (int i = 0; i < GMM_D; ++i)
        Wv[i][r] = w[i];          // consecutive addresses: conflict-free
    __syncthreads();

    // ---- tv = -(W mu): NEGATED so estep's MFMA C-init needs no negate ----
    {
        const float* mk = mus + k * GMM_D;
        float s0 = 0.f, s1 = 0.f, s2 = 0.f, s3 = 0.f;
        #pragma unroll
        for (int c = 0; c < GMM_D; c += 4) {
            s0 += Wv[r][c + 0] * mk[c + 0];
            s1 += Wv[r][c + 1] * mk[c + 1];
            s2 += Wv[r][c + 2] * mk[c + 2];
            s3 += Wv[r][c + 3] * mk[c + 3];
        }
        tv[k * GMM_D + r] = -((s0 + s1) + (s2 + s3));
    }

    // ---- swizzle W -> f16 hi/lo A-fragments (16x16x32 layout, R6/R9) ----
    // frag f = mt*4+s: lane L elem u = W[mt*16 + (L&15)][(s&1)*32 + (L>>4)*8 + u],
    // s in {0,1}: hi ; {2,3}: lo. 16B/lane stores, coalesced.
    {
        const int lr = r & 15, q = r >> 4;
        #pragma unroll
        for (int f = 0; f < 16; ++f) {
            const int mt = f >> 2, s = f & 3;
            const int row = mt * 16 + lr;
            const int db = (s & 1) * 32 + q * 8;
            half8 hv;
            #pragma unroll
            for (int u = 0; u < 8; ++u) {
                const float v = Wv[row][db + u];
                _Float16 h = (_Float16)v;
                if (s >= 2) h = (_Float16)(v - (float)h);
                hv[u] = h;
            }
            *(half8*)(WA + ((size_t)((k * 16 + f) * 64) + r) * 8) = hv;
        }
    }

    // ---- c_k = log pi_k - sum(log L_ii) - 0.5*D*log(2*pi) ----
    {
        float ll = logf(mydiag);
        #pragma unroll
        for (int off = 32; off > 0; off >>= 1) ll += __shfl_down(ll, off);
        if (r == 0)
            cc[k] = logf(pi[k]) - ll - 0.5f * 64.0f * 1.8378770664093453f;
    }
}

// ---------------------------------------------------------------------------
// E-step (R9 structure): block = 4 waves, 64 points; wave w owns comps
// 4w..4w+3. Per (comp, ntile): 4 Mtiles x 6 MFMA 16x16x32 f16 (hi*hi +
// hi*lo + lo*hi), C preloaded with -t (tv negated), maha reduced in-register
// + 2 shfl_xor. __launch_bounds__(256,4): cap total VGPR+AGPR at 128/wave
// so >=4 waves/SIMD stay resident (latency-bound kernel; see header).
// ---------------------------------------------------------------------------
__global__ __launch_bounds__(256, 4) void gmm_estep_kernel(
    const float* __restrict__ X, const _Float16* __restrict__ WA,
    const float* __restrict__ tv, const float* __restrict__ cc,
    float* __restrict__ out, int N)
{
    // xs row (per point): [hi 0..63 | lo 0..63 | pad 8] f16 = 136 (272 B)
    __shared__ _Float16 xs[64 * 136];
    __shared__ float lg[64 * 17];

    const int tid = threadIdx.x;

    // ---- stage X -> f16 hi/lo in LDS: thread t: point t/4, dims (t%4)*16 ----
    {
        const int p = tid >> 2, qq = tid & 3;
        const int np = blockIdx.x * 64 + p;
        if (np < N) {
            const float4* src = reinterpret_cast<const float4*>(X + (size_t)np * GMM_D) + qq * 4;
            float vv[16];
            #pragma unroll
            for (int u = 0; u < 4; ++u) {
                const float4 v = src[u];
                vv[4 * u + 0] = v.x; vv[4 * u + 1] = v.y;
                vv[4 * u + 2] = v.z; vv[4 * u + 3] = v.w;
            }
            half8 h0, h1, l0, l1;
            #pragma unroll
            for (int u = 0; u < 8; ++u) {
                const _Float16 a = (_Float16)vv[u];
                const _Float16 b = (_Float16)vv[u + 8];
                h0[u] = a; l0[u] = (_Float16)(vv[u] - (float)a);
                h1[u] = b; l1[u] = (_Float16)(vv[u + 8] - (float)b);
            }
            _Float16* row = xs + p * 136;
            *(half8*)(row + qq * 16)          = h0;
            *(half8*)(row + qq * 16 + 8)      = h1;
            *(half8*)(row + 64 + qq * 16)     = l0;
            *(half8*)(row + 64 + qq * 16 + 8) = l1;
        }
    }
    __syncthreads();

    const int lane = tid & 63;
    const int wave = __builtin_amdgcn_readfirstlane(tid >> 6);
    const int pt = lane & 15;
    const int q  = lane >> 4;

    #pragma unroll 1
    for (int kk = 0; kk < 4; ++kk) {
        const int k = wave * 4 + kk;  // wave-uniform

        // A fragments: 16 x global_load_dwordx4, coalesced, L2-resident.
        half8 af[4][4];
        const _Float16* wab = WA + (size_t)k * 8192 + lane * 8;
        #pragma unroll
        for (int mt = 0; mt < 4; ++mt)
            #pragma unroll
            for (int s = 0; s < 4; ++s)
                af[mt][s] = *(const half8*)(wab + (mt * 4 + s) * 512);

        // nt-invariant accumulator inits: tv holds -t, so no negate needed
        f32x4 tk4[4];
        #pragma unroll
        for (int mt = 0; mt < 4; ++mt)
            tk4[mt] = *(const f32x4*)(tv + k * 64 + mt * 16 + q * 4);

        #pragma unroll 1
        for (int nt = 0; nt < 4; ++nt) {
            const _Float16* xrow = xs + (nt * 16 + pt) * 136 + q * 8;
            const half8 bh0 = *(const half8*)(xrow);        // hi dims 0..31
            const half8 bh1 = *(const half8*)(xrow + 32);   // hi dims 32..63
            const half8 bl0 = *(const half8*)(xrow + 64);   // lo dims 0..31
            const half8 bl1 = *(const half8*)(xrow + 96);   // lo dims 32..63

            float mahaP = 0.0f;
            #pragma unroll
            for (int mt = 0; mt < 4; ++mt) {
                f32x4 c = tk4[mt];   // = -t (pre-negated in precompute)
                c = __builtin_amdgcn_mfma_f32_16x16x32_f16(af[mt][0], bh0, c, 0, 0, 0);
                c = __builtin_amdgcn_mfma_f32_16x16x32_f16(af[mt][1], bh1, c, 0, 0, 0);
                c = __builtin_amdgcn_mfma_f32_16x16x32_f16(af[mt][0], bl0, c, 0, 0, 0);
                c = __builtin_amdgcn_mfma_f32_16x16x32_f16(af[mt][1], bl1, c, 0, 0, 0);
                c = __builtin_amdgcn_mfma_f32_16x16x32_f16(af[mt][2], bh0, c, 0, 0, 0);
                c = __builtin_amdgcn_mfma_f32_16x16x32_f16(af[mt][3], bh1, c, 0, 0, 0);
                mahaP += c[0] * c[0] + c[1] * c[1] + c[2] * c[2] + c[3] * c[3];
            }
            mahaP += __shfl_xor(mahaP, 16);
            mahaP += __shfl_xor(mahaP, 32);
            if (q == 0 && (blockIdx.x * 64 + nt * 16 + pt) < N)
                lg[(nt * 16 + pt) * 17 + k] = cc[k] - 0.5f * mahaP;
        }
    }
    __syncthreads();

    // softmax: 4 threads/point, one float4 each (contiguous stores)
    {
        const int p = tid >> 2, qq = tid & 3;
        const int np = blockIdx.x * 64 + p;
        if (np < N) {
            const float* row = &lg[p * 17];
            float m = row[0];
            #pragma unroll
            for (int j = 1; j < GMM_K; ++j) m = fmaxf(m, row[j]);
            float e[GMM_K];
            float s = 0.0f;
            #pragma unroll
            for (int j = 0; j < GMM_K; ++j) { e[j] = __expf(row[j] - m); s += e[j]; }
            const float inv = 1.0f / s;
            float4 v;
            v.x = e[qq * 4 + 0] * inv;
            v.y = e[qq * 4 + 1] * inv;
            v.z = e[qq * 4 + 2] * inv;
            v.w = e[qq * 4 + 3] * inv;
            reinterpret_cast<float4*>(out + (size_t)np * GMM_K)[qq] = v;
        }
    }
}

// ---------------------------------------------------------------------------
extern "C" void kernel_launch(void* const* d_in, const int* in_sizes, int n_in,
                              void* d_out, int out_size, void* d_ws, size_t ws_size,
                              hipStream_t stream)
{
    const float* X    = (const float*)d_in[0];
    const float* pi   = (const float*)d_in[1];
    const float* mus  = (const float*)d_in[2];
    const float* covs = (const float*)d_in[3];
    float* out = (float*)d_out;

    const int N = in_sizes[0] / GMM_D;

    _Float16* WA = (_Float16*)d_ws;
    float* tv = (float*)((char*)d_ws + WA_BYTES);
    float* cc = tv + GMM_K * GMM_D;

    gmm_precompute_kernel<<<dim3(GMM_K), dim3(64), 0, stream>>>(pi, mus, covs, WA, tv, cc);

    const int blocks = (N + 63) / 64;  // 200000/64 = 3125 exactly
    gmm_estep_kernel<<<dim3(blocks), dim3(256), 0, stream>>>(X, WA, tv, cc, out, N);
}

// Round 10
// 173.905 us; speedup vs baseline: 1.0404x; 1.0404x over previous
//
#include <hip/hip_runtime.h>
#include <cstddef>
#include <cstdint>

// GMM E-step: N=200000, K=16, D=64, fp32 in/out.
// R15: verified R9 kernel (total 176us, estep 71.5us) with ONE change:
// __launch_bounds__(256, 2) on estep (register CEILING 256, was implicit
// ~60). Evidence: VGPR_Count=60 < af[4][4]'s 64 regs proves the compiler
// re-loads af from L2 per nt-tile (192 extra L2 loads/wave/kk @ ~200cyc);
// R13's cap-128 spilled 50MB -> compiler's unconstrained preference >128.
// With min-waves=2 the allocator may keep af+tk4 across the nt loop and
// prefetch kk+1. Zero-restructure, zero correctness risk. R14's two-pass
// LDS halving failed post-timing verification unexplainably -> abandoned
// (unverifiable structures don't ship). setprio out (R12 null),
// launch_bounds(256,4) out (R13 spills).
// Precompute = R9 verified (single-wave register Cholesky + LDS handoff +
// register fwd-subst inverse, negated tv, 16x16 WA swizzle).

#define GMM_D 64
#define GMM_K 16

typedef _Float16 half8 __attribute__((ext_vector_type(8)));
typedef float f32x4 __attribute__((ext_vector_type(4)));

// ws: WA [16 comps][16 frags][64 lanes][8 f16] = 262144 B, then tv, cc (f32)
#define WA_BYTES (GMM_K * 16 * 64 * 8 * 2)

__device__ __forceinline__ float fast_rsqrt(float x) {
#if __has_builtin(__builtin_amdgcn_rsqf)
    // v_rsq_f32 (~1 ulp) + one Newton step -> full fp32 accuracy
    const float r = __builtin_amdgcn_rsqf(x);
    return r * (1.5f - 0.5f * x * r * r);
#else
    return 1.0f / sqrtf(x);
#endif
}

// broadcast lane l's value of v to all lanes (l compile-time after unroll)
__device__ __forceinline__ float lane_bcast(float v, int l) {
    return __int_as_float(__builtin_amdgcn_readlane(__float_as_int(v), l));
}

// ---------------------------------------------------------------------------
// Precompute (R9-verified): one WAVE per component. Phase 1: register
// Cholesky via readlane broadcasts. Phase 2: register forward-substitution
// inverse fed by wave-uniform ds_read_b128 of L rows. At most one 64-float
// register array live at a time (R7 lesson: two live arrays -> spills).
// tv stored NEGATED so estep's MFMA C-init needs no negate (R9).
// ---------------------------------------------------------------------------
__global__ __launch_bounds__(64) void gmm_precompute_kernel(
    const float* __restrict__ pi, const float* __restrict__ mus,
    const float* __restrict__ covs, _Float16* __restrict__ WA,
    float* __restrict__ tv, float* __restrict__ cc)
{
    const int k = blockIdx.x;
    const int r = threadIdx.x;  // lane id

    __shared__ alignas(16) float Ls[GMM_D][68];  // L rows, upper tri zeroed;
                                                 // 272 B stride: 16B-aligned
    __shared__ float Wv[GMM_D][GMM_D + 1];       // W = L^{-1}, for epilogue

    // ---- load row r of Sigma into registers (16x float4, L2-resident) ----
    float A_r[GMM_D];
    {
        const float4* src = reinterpret_cast<const float4*>(
            covs + (size_t)k * GMM_D * GMM_D + (size_t)r * GMM_D);
        #pragma unroll
        for (int u = 0; u < GMM_D / 4; ++u) {
            const float4 v = src[u];
            A_r[4 * u + 0] = v.x; A_r[4 * u + 1] = v.y;
            A_r[4 * u + 2] = v.z; A_r[4 * u + 3] = v.w;
        }
    }

    // ---- Phase 1: register Cholesky, right-looking, zero barriers ----
    float mydiag = 1.0f, myrs = 1.0f;
    #pragma unroll
    for (int j = 0; j < GMM_D; ++j) {
        const float pivot = lane_bcast(A_r[j], j);   // lane j: valid diag
        const float rs = fast_rsqrt(pivot);
        const float valj = A_r[j] * rs;              // L[r][j]; lane j: sqrt(pivot)
        if (r == j) { mydiag = valj; myrs = rs; }
        A_r[j] = valj;
        #pragma unroll
        for (int p = j + 1; p < GMM_D; ++p)          // rank-1 trailing update
            A_r[p] -= valj * lane_bcast(valj, p);    // L[p][j] from lane p
    }

    // ---- handoff: dump L rows to LDS, upper triangle zeroed. A_r dies. ----
    #pragma unroll
    for (int p = 0; p < GMM_D; ++p)
        Ls[r][p] = (p <= r) ? A_r[p] : 0.0f;
    __syncthreads();   // single wave: cheap

    // ---- Phase 2: lane r solves L w = e_r; only w[64] live in registers ----
    float w[GMM_D];
    #pragma unroll
    for (int i = 0; i < GMM_D; ++i) w[i] = 0.0f;

    #pragma unroll
    for (int i = 0; i < GMM_D; ++i) {
        const f32x4* Lrow = reinterpret_cast<const f32x4*>(&Ls[i][0]);
        float a0 = 0.0f, a1 = 0.0f, a2 = 0.0f, a3 = 0.0f;
        #pragma unroll
        for (int u = 0; u <= (i >> 2); ++u) {        // zeros make tail exact
            const f32x4 lv = Lrow[u];
            a0 -= lv[0] * w[4 * u + 0];
            a1 -= lv[1] * w[4 * u + 1];
            a2 -= lv[2] * w[4 * u + 2];
            a3 -= lv[3] * w[4 * u + 3];
        }
        const float invd = lane_bcast(myrs, i);      // 1/L[i][i]
        const float dlt = (r == i) ? 1.0f : 0.0f;
        w[i] = (dlt + (a0 + a1) + (a2 + a3)) * invd;
    }

    // ---- dump W to LDS (lane r holds column r -> write transposed) ----
    #pragma unroll
    for (int i = 0; i < GMM_D; ++i)
        Wv[i][r] = w[i];          // consecutive addresses: conflict-free
    __syncthreads();

    // ---- tv = -(W mu): NEGATED so estep's MFMA C-init needs no negate ----
    {
        const float* mk = mus + k * GMM_D;
        float s0 = 0.f, s1 = 0.f, s2 = 0.f, s3 = 0.f;
        #pragma unroll
        for (int c = 0; c < GMM_D; c += 4) {
            s0 += Wv[r][c + 0] * mk[c + 0];
            s1 += Wv[r][c + 1] * mk[c + 1];
            s2 += Wv[r][c + 2] * mk[c + 2];
            s3 += Wv[r][c + 3] * mk[c + 3];
        }
        tv[k * GMM_D + r] = -((s0 + s1) + (s2 + s3));
    }

    // ---- swizzle W -> f16 hi/lo A-fragments (16x16x32 layout, R6/R9) ----
    // frag f = mt*4+s: lane L elem u = W[mt*16 + (L&15)][(s&1)*32 + (L>>4)*8 + u],
    // s in {0,1}: hi ; {2,3}: lo. 16B/lane stores, coalesced.
    {
        const int lr = r & 15, q = r >> 4;
        #pragma unroll
        for (int f = 0; f < 16; ++f) {
            const int mt = f >> 2, s = f & 3;
            const int row = mt * 16 + lr;
            const int db = (s & 1) * 32 + q * 8;
            half8 hv;
            #pragma unroll
            for (int u = 0; u < 8; ++u) {
                const float v = Wv[row][db + u];
                _Float16 h = (_Float16)v;
                if (s >= 2) h = (_Float16)(v - (float)h);
                hv[u] = h;
            }
            *(half8*)(WA + ((size_t)((k * 16 + f) * 64) + r) * 8) = hv;
        }
    }

    // ---- c_k = log pi_k - sum(log L_ii) - 0.5*D*log(2*pi) ----
    {
        float ll = logf(mydiag);
        #pragma unroll
        for (int off = 32; off > 0; off >>= 1) ll += __shfl_down(ll, off);
        if (r == 0)
            cc[k] = logf(pi[k]) - ll - 0.5f * 64.0f * 1.8378770664093453f;
    }
}

// ---------------------------------------------------------------------------
// E-step (R9 structure, verified): block = 4 waves, 64 points; wave w owns
// comps 4w..4w+3. Per (comp, ntile): 4 Mtiles x 6 MFMA 16x16x32 f16 (hi*hi +
// hi*lo + lo*hi), C preloaded with -t (tv negated), maha reduced in-register
// + 2 shfl_xor. __launch_bounds__(256,2): register ceiling 256 so the
// allocator can keep af[4][4]+tk4 resident across nt and prefetch kk+1
// (at VGPR=60 it re-loads af per nt from L2 - 192 extra loads/wave/kk).
// ---------------------------------------------------------------------------
__global__ __launch_bounds__(256, 2) void gmm_estep_kernel(
    const float* __restrict__ X, const _Float16* __restrict__ WA,
    const float* __restrict__ tv, const float* __restrict__ cc,
    float* __restrict__ out, int N)
{
    // xs row (per point): [hi 0..63 | lo 0..63 | pad 8] f16 = 136 (272 B)
    __shared__ _Float16 xs[64 * 136];
    __shared__ float lg[64 * 17];

    const int tid = threadIdx.x;

    // ---- stage X -> f16 hi/lo in LDS: thread t: point t/4, dims (t%4)*16 ----
    {
        const int p = tid >> 2, qq = tid & 3;
        const int np = blockIdx.x * 64 + p;
        if (np < N) {
            const float4* src = reinterpret_cast<const float4*>(X + (size_t)np * GMM_D) + qq * 4;
            float vv[16];
            #pragma unroll
            for (int u = 0; u < 4; ++u) {
                const float4 v = src[u];
                vv[4 * u + 0] = v.x; vv[4 * u + 1] = v.y;
                vv[4 * u + 2] = v.z; vv[4 * u + 3] = v.w;
            }
            half8 h0, h1, l0, l1;
            #pragma unroll
            for (int u = 0; u < 8; ++u) {
                const _Float16 a = (_Float16)vv[u];
                const _Float16 b = (_Float16)vv[u + 8];
                h0[u] = a; l0[u] = (_Float16)(vv[u] - (float)a);
                h1[u] = b; l1[u] = (_Float16)(vv[u + 8] - (float)b);
            }
            _Float16* row = xs + p * 136;
            *(half8*)(row + qq * 16)          = h0;
            *(half8*)(row + qq * 16 + 8)      = h1;
            *(half8*)(row + 64 + qq * 16)     = l0;
            *(half8*)(row + 64 + qq * 16 + 8) = l1;
        }
    }
    __syncthreads();

    const int lane = tid & 63;
    const int wave = __builtin_amdgcn_readfirstlane(tid >> 6);
    const int pt = lane & 15;
    const int q  = lane >> 4;

    #pragma unroll 1
    for (int kk = 0; kk < 4; ++kk) {
        const int k = wave * 4 + kk;  // wave-uniform

        // A fragments: 16 x global_load_dwordx4, coalesced, L2-resident.
        half8 af[4][4];
        const _Float16* wab = WA + (size_t)k * 8192 + lane * 8;
        #pragma unroll
        for (int mt = 0; mt < 4; ++mt)
            #pragma unroll
            for (int s = 0; s < 4; ++s)
                af[mt][s] = *(const half8*)(wab + (mt * 4 + s) * 512);

        // nt-invariant accumulator inits: tv holds -t, so no negate needed
        f32x4 tk4[4];
        #pragma unroll
        for (int mt = 0; mt < 4; ++mt)
            tk4[mt] = *(const f32x4*)(tv + k * 64 + mt * 16 + q * 4);

        #pragma unroll 1
        for (int nt = 0; nt < 4; ++nt) {
            const _Float16* xrow = xs + (nt * 16 + pt) * 136 + q * 8;
            const half8 bh0 = *(const half8*)(xrow);        // hi dims 0..31
            const half8 bh1 = *(const half8*)(xrow + 32);   // hi dims 32..63
            const half8 bl0 = *(const half8*)(xrow + 64);   // lo dims 0..31
            const half8 bl1 = *(const half8*)(xrow + 96);   // lo dims 32..63

            float mahaP = 0.0f;
            #pragma unroll
            for (int mt = 0; mt < 4; ++mt) {
                f32x4 c = tk4[mt];   // = -t (pre-negated in precompute)
                c = __builtin_amdgcn_mfma_f32_16x16x32_f16(af[mt][0], bh0, c, 0, 0, 0);
                c = __builtin_amdgcn_mfma_f32_16x16x32_f16(af[mt][1], bh1, c, 0, 0, 0);
                c = __builtin_amdgcn_mfma_f32_16x16x32_f16(af[mt][0], bl0, c, 0, 0, 0);
                c = __builtin_amdgcn_mfma_f32_16x16x32_f16(af[mt][1], bl1, c, 0, 0, 0);
                c = __builtin_amdgcn_mfma_f32_16x16x32_f16(af[mt][2], bh0, c, 0, 0, 0);
                c = __builtin_amdgcn_mfma_f32_16x16x32_f16(af[mt][3], bh1, c, 0, 0, 0);
                mahaP += c[0] * c[0] + c[1] * c[1] + c[2] * c[2] + c[3] * c[3];
            }
            mahaP += __shfl_xor(mahaP, 16);
            mahaP += __shfl_xor(mahaP, 32);
            if (q == 0 && (blockIdx.x * 64 + nt * 16 + pt) < N)
                lg[(nt * 16 + pt) * 17 + k] = cc[k] - 0.5f * mahaP;
        }
    }
    __syncthreads();

    // softmax: 4 threads/point, one float4 each (contiguous stores)
    {
        const int p = tid >> 2, qq = tid & 3;
        const int np = blockIdx.x * 64 + p;
        if (np < N) {
            const float* row = &lg[p * 17];
            float m = row[0];
            #pragma unroll
            for (int j = 1; j < GMM_K; ++j) m = fmaxf(m, row[j]);
            float e[GMM_K];
            float s = 0.0f;
            #pragma unroll
            for (int j = 0; j < GMM_K; ++j) { e[j] = __expf(row[j] - m); s += e[j]; }
            const float inv = 1.0f / s;
            float4 v;
            v.x = e[qq * 4 + 0] * inv;
            v.y = e[qq * 4 + 1] * inv;
            v.z = e[qq * 4 + 2] * inv;
            v.w = e[qq * 4 + 3] * inv;
            reinterpret_cast<float4*>(out + (size_t)np * GMM_K)[qq] = v;
        }
    }
}

// ---------------------------------------------------------------------------
extern "C" void kernel_launch(void* const* d_in, const int* in_sizes, int n_in,
                              void* d_out, int out_size, void* d_ws, size_t ws_size,
                              hipStream_t stream)
{
    const float* X    = (const float*)d_in[0];
    const float* pi   = (const float*)d_in[1];
    const float* mus  = (const float*)d_in[2];
    const float* covs = (const float*)d_in[3];
    float* out = (float*)d_out;

    const int N = in_sizes[0] / GMM_D;

    _Float16* WA = (_Float16*)d_ws;
    float* tv = (float*)((char*)d_ws + WA_BYTES);
    float* cc = tv + GMM_K * GMM_D;

    gmm_precompute_kernel<<<dim3(GMM_K), dim3(64), 0, stream>>>(pi, mus, covs, WA, tv, cc);

    const int blocks = (N + 63) / 64;  // 200000/64 = 3125 exactly
    gmm_estep_kernel<<<dim3(blocks), dim3(256), 0, stream>>>(X, WA, tv, cc, out, N);
}